// Round 1
// baseline (80.473 us; speedup 1.0000x reference)
//
#include <hip/hip_runtime.h>
#include <hip/hip_bf16.h>
#include <stdint.h>

// Problem dims
#define M_DIM 8000
#define K_DIM 120
#define N_DIM 8000
#define M_PADD 8064   // padded M (and padded N for B^T storage)
#define K_PADD 128    // padded K

typedef __attribute__((ext_vector_type(8))) __bf16 bf16x8;
typedef __attribute__((ext_vector_type(4))) float f32x4;
typedef __attribute__((ext_vector_type(8))) unsigned short u16x8;

__device__ __forceinline__ unsigned short f2bf(float f) {
  unsigned int u = __builtin_bit_cast(unsigned int, f);
  u += 0x7FFFu + ((u >> 16) & 1u);   // round-to-nearest-even
  return (unsigned short)(u >> 16);
}

// A [8000][120] f32  ->  Abf [8064][128] bf16, zero-padded, row-swizzled.
// Element (row,k) stored at byte: row*256 + ((2k) ^ ((row&7)<<4)).
__global__ __launch_bounds__(256) void conv_a_kernel(const float* __restrict__ A,
                                                     unsigned short* __restrict__ Abf) {
  int t = blockIdx.x * 256 + threadIdx.x;
  if (t >= M_PADD * 16) return;
  int row = t >> 4;     // 0..8063
  int kg  = t & 15;     // k-group of 8 elems
  u16x8 v = (u16x8)0;
  if (row < M_DIM && kg < 15) {   // kg=14 covers k=112..119 (<120); kg=15 is pad
    const float* src = A + (size_t)row * K_DIM + kg * 8;   // 32B-aligned (480%32==0)
    float4 f0 = *(const float4*)(src);
    float4 f1 = *(const float4*)(src + 4);
    v[0] = f2bf(f0.x); v[1] = f2bf(f0.y); v[2] = f2bf(f0.z); v[3] = f2bf(f0.w);
    v[4] = f2bf(f1.x); v[5] = f2bf(f1.y); v[6] = f2bf(f1.z); v[7] = f2bf(f1.w);
  }
  int off = (kg * 16) ^ ((row & 7) << 4);
  *(u16x8*)((char*)Abf + (size_t)row * 256 + off) = v;
}

// Bm [120][8000] f32 -> Bbf [8064][128] bf16 = B^T, zero-padded, row-swizzled.
// Bbf element (n,k) = Bm[k][n], stored at byte: n*256 + ((2k) ^ ((n&7)<<4)).
__global__ __launch_bounds__(256) void conv_b_kernel(const float* __restrict__ B,
                                                     unsigned short* __restrict__ Bbf) {
  int t = blockIdx.x * 256 + threadIdx.x;
  if (t >= M_PADD * 16) return;
  int kg = t / M_PADD;  // 0..15 (uniform-ish per block -> coalesced reads over n)
  int n  = t % M_PADD;  // 0..8063
  u16x8 v = (u16x8)0;
  if (n < N_DIM && kg < 15) {
    const float* src = B + (size_t)(kg * 8) * N_DIM + n;
#pragma unroll
    for (int j = 0; j < 8; ++j) v[j] = f2bf(src[(size_t)j * N_DIM]);
  }
  int off = (kg * 16) ^ ((n & 7) << 4);
  *(u16x8*)((char*)Bbf + (size_t)n * 256 + off) = v;
}

// 128x128 output tile per block, 4 waves (2x2 of 64x64), single K-tile (K=128).
__global__ __launch_bounds__(256) void gemm_bias_kernel(const unsigned short* __restrict__ Abf,
                                                        const unsigned short* __restrict__ Bbf,
                                                        const float* __restrict__ bias,
                                                        float* __restrict__ out) {
  __shared__ __align__(16) char smem[65536];   // As: [0,32K), Bs: [32K,64K)
  const int bn = blockIdx.x;
  const int bm = blockIdx.y;
  const int tid  = threadIdx.x;
  const int lane = tid & 63;
  const int wave = tid >> 6;
  const int wr = wave >> 1;   // 0..1
  const int wc = wave & 1;    // 0..1

  // Stage both 32KB tiles (linear copies; source is pre-swizzled in global).
  const char* gA = (const char*)Abf + (size_t)bm * 32768;
  const char* gB = (const char*)Bbf + (size_t)bn * 32768;
#pragma unroll
  for (int i = 0; i < 8; ++i) {
    int off = i * 4096 + wave * 1024;
    __builtin_amdgcn_global_load_lds(
        (const __attribute__((address_space(1))) void*)(gA + off + lane * 16),
        (__attribute__((address_space(3))) void*)(smem + off), 16, 0, 0);
  }
#pragma unroll
  for (int i = 0; i < 8; ++i) {
    int off = i * 4096 + wave * 1024;
    __builtin_amdgcn_global_load_lds(
        (const __attribute__((address_space(1))) void*)(gB + off + lane * 16),
        (__attribute__((address_space(3))) void*)(smem + 32768 + off), 16, 0, 0);
  }
  __syncthreads();   // drains vmcnt before barrier

  f32x4 acc[4][4] = {};
  const int l15 = lane & 15;
  const int kq  = lane >> 4;          // 0..3
#pragma unroll
  for (int ks = 0; ks < 4; ++ks) {
    const int kb = (ks * 32 + kq * 8) * 2;   // byte offset along K (mult of 16)
    bf16x8 a[4], b[4];
#pragma unroll
    for (int m = 0; m < 4; ++m) {
      int row = wr * 64 + m * 16 + l15;
      a[m] = *(const bf16x8*)(smem + (size_t)row * 256 + (kb ^ ((row & 7) << 4)));
    }
#pragma unroll
    for (int n = 0; n < 4; ++n) {
      int row = wc * 64 + n * 16 + l15;
      b[n] = *(const bf16x8*)(smem + 32768 + (size_t)row * 256 + (kb ^ ((row & 7) << 4)));
    }
#pragma unroll
    for (int m = 0; m < 4; ++m)
#pragma unroll
      for (int n = 0; n < 4; ++n)
        acc[m][n] = __builtin_amdgcn_mfma_f32_16x16x32_bf16(a[m], b[n], acc[m][n], 0, 0, 0);
  }

  // Epilogue: C/D layout col = lane&15, row = (lane>>4)*4 + reg  [m89-verified]
  const int row0 = bm * 128 + wr * 64 + kq * 4;
  const int col0 = bn * 128 + wc * 64;
#pragma unroll
  for (int n = 0; n < 4; ++n) {
    const int gcol = col0 + n * 16 + l15;
    if (gcol >= N_DIM) continue;            // wave-uniform (8000 % 16 == 0)
    const float bv = bias[gcol];
#pragma unroll
    for (int m = 0; m < 4; ++m) {
      const int grow = row0 + m * 16;
#pragma unroll
      for (int r = 0; r < 4; ++r)
        out[(size_t)(grow + r) * N_DIM + gcol] = acc[m][n][r] + bv;
    }
  }
}

// Safety net if ws_size is too small for the bf16 staging buffers.
__global__ __launch_bounds__(256) void fallback_kernel(const float* __restrict__ A,
                                                       const float* __restrict__ B,
                                                       const float* __restrict__ bias,
                                                       float* __restrict__ out) {
  size_t idx = (size_t)blockIdx.x * 256 + threadIdx.x;
  if (idx >= (size_t)M_PADD * N_DIM) return;
  int col = (int)(idx % N_DIM);
  int row = (int)(idx / N_DIM);
  float s = 0.f;
  if (row < M_DIM) {
    for (int k = 0; k < K_DIM; ++k)
      s += A[(size_t)row * K_DIM + k] * B[(size_t)k * N_DIM + col];
  }
  out[idx] = s + bias[col];
}

extern "C" void kernel_launch(void* const* d_in, const int* in_sizes, int n_in,
                              void* d_out, int out_size, void* d_ws, size_t ws_size,
                              hipStream_t stream) {
  const float* A    = (const float*)d_in[0];
  const float* Bm   = (const float*)d_in[1];
  const float* bias = (const float*)d_in[2];
  float* out = (float*)d_out;

  const size_t abf_elems = (size_t)M_PADD * K_PADD;            // 1,032,192
  const size_t need = abf_elems * 2 * sizeof(unsigned short);  // ~4.13 MB
  if (ws_size < need) {
    size_t total = (size_t)M_PADD * N_DIM;
    fallback_kernel<<<dim3((unsigned)((total + 255) / 256)), dim3(256), 0, stream>>>(A, Bm, bias, out);
    return;
  }

  unsigned short* Abf = (unsigned short*)d_ws;
  unsigned short* Bbf = Abf + abf_elems;   // 16B-aligned (offset 2,064,384)

  const int convBlocks = (M_PADD * 16 + 255) / 256;   // 504
  conv_a_kernel<<<dim3(convBlocks), dim3(256), 0, stream>>>(A, Abf);
  conv_b_kernel<<<dim3(convBlocks), dim3(256), 0, stream>>>(Bm, Bbf);
  gemm_bias_kernel<<<dim3(63, 63), dim3(256), 0, stream>>>(Abf, Bbf, bias, out);
}